// Round 9
// baseline (103.546 us; speedup 1.0000x reference)
//
#include <hip/hip_runtime.h>

// FastSAM3DPromptEncoder: out[b,n,c] = pos_embed[0,c,z,y,x] + point_emb[labels[b,n],c]
// (z,y,x) = clamp(trunc(points[b,n,:]), 0, 63).
//
// Counting-sort points by 64-B-line key (z,y,x>>4) into fixed-capacity bin
// segments (single atomic scatter pass), then bin-centric gather:
// 16 bins/block (1-KB DRAM runs per channel plane, 1024 blocks = all
// resident), double-buffered LDS tile, DEPTH-2 software pipeline (bin k+2
// issued while bin k computes; load-to-use spans a full iteration).

constexpr int B_ = 32;
constexpr int N_ = 4096;
constexpr int C_ = 256;
constexpr int GD = 64;
constexpr int PTS = B_ * N_;               // 131072
constexpr int CELLS = GD * GD * GD;        // 262144 (channel stride)
constexpr int NBINS = GD * GD * (GD / 16); // 16384 line keys
constexpr int CAP = 64;                    // slots per bin (avg 8; P(>64)~1e-33)
constexpr int BPB = 16;                    // bins per block
constexpr int NBLK = NBINS / BPB;          // 1024 blocks
constexpr int TP = 260;                    // padded tile row stride (floats)

typedef float f32x4 __attribute__((ext_vector_type(4)));  // native vec for nt-store

__device__ __forceinline__ int clamp63(float v) {
    int i = (int)v;
    return min(max(i, 0), GD - 1);
}

__device__ __forceinline__ size_t linebase(int bin) {
    return ((size_t)(bin >> 8) << 12) | ((size_t)((bin >> 2) & 63) << 6) |
           ((size_t)(bin & 3) << 4);
}

// ---- K1: scatter packed point records into fixed-capacity bin segments ----
// rec = p (17b) | lab (1b @17) | x&15 (4b @18)
__global__ __launch_bounds__(256) void k_scatter(const float* __restrict__ points,
                                                 const int* __restrict__ labels,
                                                 unsigned* __restrict__ counts,
                                                 unsigned* __restrict__ recs,
                                                 const float* __restrict__ pos,
                                                 const float* __restrict__ pemb,
                                                 float* __restrict__ out) {
    int p = blockIdx.x * blockDim.x + threadIdx.x;
    if (p >= PTS) return;
    int zi = clamp63(points[p * 3 + 0]);
    int yi = clamp63(points[p * 3 + 1]);
    int xi = clamp63(points[p * 3 + 2]);
    int key = (zi << 8) | (yi << 2) | (xi >> 4);
    int lab = labels[p];
    unsigned slot = atomicAdd(&counts[key], 1u);
    if (slot < CAP) {
        recs[key * CAP + slot] =
            (unsigned)p | ((unsigned)lab << 17) | ((unsigned)(xi & 15) << 18);
    } else {
        // statistically unreachable overflow: write this point's row directly
        const int cell = (zi << 12) | (yi << 6) | xi;
        for (int c = 0; c < C_; ++c)
            out[(size_t)p * C_ + c] = pos[(size_t)c * CELLS + cell] + pemb[lab * C_ + c];
    }
}

// ---- K2: depth-2 pipelined bin-centric gather. 16 bins/block, dbuf LDS ----
__global__ __launch_bounds__(256) void k_gather(const unsigned* __restrict__ counts,
                                                const unsigned* __restrict__ recs,
                                                const float* __restrict__ pos,
                                                const float* __restrict__ pemb,
                                                float* __restrict__ out) {
    __shared__ float tile[2][16 * TP];      // 2 x 16.6 KB

    // XCD-chunked swizzle: each XCD owns a contiguous bin super-range.
    const int b    = blockIdx.x;
    const int swz  = (b & 7) * (NBLK >> 3) + (b >> 3);
    const int bin0 = swz * BPB;

    const int tid  = threadIdx.x;
    const int w    = tid >> 6;
    const int l    = tid & 63;
    const int o4   = (tid & 3) << 2;        // x-offset group for staging
    const int csub = tid >> 2;              // 0..63 channel sub-index

    // point_emb rows for this lane's 4 channels, hoisted to registers
    const float4 te0 = *reinterpret_cast<const float4*>(pemb + 4 * l);
    const float4 te1 = *reinterpret_cast<const float4*>(pemb + C_ + 4 * l);

#define LOADBIN(r0, r1, r2, r3, BIN) {                                              \
        const size_t lb_ = linebase(BIN);                                           \
        r0 = *reinterpret_cast<const float4*>(pos + (size_t)(  0 + csub) * CELLS + lb_ + o4); \
        r1 = *reinterpret_cast<const float4*>(pos + (size_t)( 64 + csub) * CELLS + lb_ + o4); \
        r2 = *reinterpret_cast<const float4*>(pos + (size_t)(128 + csub) * CELLS + lb_ + o4); \
        r3 = *reinterpret_cast<const float4*>(pos + (size_t)(192 + csub) * CELLS + lb_ + o4); \
    }
#define WRITEBIN(r0, r1, r2, r3, DST) {                                             \
        float* t_ = (DST);                                                          \
        t_[(o4 + 0) * TP +   0 + csub] = r0.x; t_[(o4 + 1) * TP +   0 + csub] = r0.y; \
        t_[(o4 + 2) * TP +   0 + csub] = r0.z; t_[(o4 + 3) * TP +   0 + csub] = r0.w; \
        t_[(o4 + 0) * TP +  64 + csub] = r1.x; t_[(o4 + 1) * TP +  64 + csub] = r1.y; \
        t_[(o4 + 2) * TP +  64 + csub] = r1.z; t_[(o4 + 3) * TP +  64 + csub] = r1.w; \
        t_[(o4 + 0) * TP + 128 + csub] = r2.x; t_[(o4 + 1) * TP + 128 + csub] = r2.y; \
        t_[(o4 + 2) * TP + 128 + csub] = r2.z; t_[(o4 + 3) * TP + 128 + csub] = r2.w; \
        t_[(o4 + 0) * TP + 192 + csub] = r3.x; t_[(o4 + 1) * TP + 192 + csub] = r3.y; \
        t_[(o4 + 2) * TP + 192 + csub] = r3.z; t_[(o4 + 3) * TP + 192 + csub] = r3.w; \
    }

    auto phase2 = [&](int k, const float* tcur) {
        const int bin = bin0 + k;
        const unsigned cnt   = min(counts[bin], (unsigned)CAP);
        const unsigned start = (unsigned)bin * CAP;
        const unsigned end   = start + cnt;
        for (unsigned i = start + w; i < end; i += 4) {
            const unsigned rec = recs[i];            // wave-uniform broadcast
            const unsigned p   = rec & 0x1FFFFu;
            const unsigned o   = rec >> 18;
            const float4 te = ((rec >> 17) & 1u) ? te1 : te0;
            const float4 v  = *reinterpret_cast<const float4*>(tcur + o * TP + 4 * l);
            f32x4 rr;
            rr.x = v.x + te.x; rr.y = v.y + te.y; rr.z = v.z + te.z; rr.w = v.w + te.w;
            __builtin_nontemporal_store(rr,
                reinterpret_cast<f32x4*>(out + (size_t)p * C_ + 4 * l));
        }
    };

    float4 ra0, ra1, ra2, ra3;   // reg set A
    float4 rb0, rb1, rb2, rb3;   // reg set B

    // prologue: bin0 staged via B; bin1 in flight in A
    LOADBIN(rb0, rb1, rb2, rb3, bin0);
    WRITEBIN(rb0, rb1, rb2, rb3, tile[0]);
    LOADBIN(ra0, ra1, ra2, ra3, bin0 + 1);

    // invariant at iter k: tile[k&1] = bin k (staged); bin k+1 in flight
    //   (even k: in A, odd k: in B)
    #pragma unroll 2
    for (int k = 0; k < BPB; ++k) {
        if (k & 1) {
            if (k + 2 < BPB) LOADBIN(ra0, ra1, ra2, ra3, bin0 + k + 2);
            __syncthreads();
            phase2(k, tile[1]);
            if (k + 1 < BPB) WRITEBIN(rb0, rb1, rb2, rb3, tile[0]);
        } else {
            if (k + 2 < BPB) LOADBIN(rb0, rb1, rb2, rb3, bin0 + k + 2);
            __syncthreads();
            phase2(k, tile[0]);
            if (k + 1 < BPB) WRITEBIN(ra0, ra1, ra2, ra3, tile[1]);
        }
    }
#undef LOADBIN
#undef WRITEBIN
}

// ---- fallback if ws too small ----
__global__ __launch_bounds__(256) void k_naive(const float* __restrict__ points,
                                               const int* __restrict__ labels,
                                               const float* __restrict__ pos,
                                               const float* __restrict__ pemb,
                                               float* __restrict__ out) {
    const int t    = blockIdx.x * blockDim.x + threadIdx.x;
    const int p    = t >> 6;
    const int lane = t & 63;
    const int c4   = lane << 2;
    if (p >= PTS) return;
    int zi = clamp63(points[p * 3 + 0]);
    int yi = clamp63(points[p * 3 + 1]);
    int xi = clamp63(points[p * 3 + 2]);
    const int cell = (zi << 12) | (yi << 6) | xi;
    const int lab  = labels[p];
    const float4 te = *reinterpret_cast<const float4*>(pemb + lab * C_ + c4);
    const float* g = pos + cell;
    float4 r;
    r.x = g[(c4 + 0) * CELLS] + te.x;
    r.y = g[(c4 + 1) * CELLS] + te.y;
    r.z = g[(c4 + 2) * CELLS] + te.z;
    r.w = g[(c4 + 3) * CELLS] + te.w;
    *reinterpret_cast<float4*>(out + p * C_ + c4) = r;
}

extern "C" void kernel_launch(void* const* d_in, const int* in_sizes, int n_in,
                              void* d_out, int out_size, void* d_ws, size_t ws_size,
                              hipStream_t stream) {
    const float* points = (const float*)d_in[0];
    const int*   labels = (const int*)d_in[1];
    const float* pos    = (const float*)d_in[2];
    const float* pemb   = (const float*)d_in[3];
    float*       out    = (float*)d_out;

    // ws layout: counts[NBINS] | recs[NBINS*CAP]
    const size_t need = (size_t)(NBINS + NBINS * CAP) * sizeof(unsigned);
    if (ws_size < need) {
        const int total = PTS * 64;
        k_naive<<<(total + 255) / 256, 256, 0, stream>>>(points, labels, pos, pemb, out);
        return;
    }
    unsigned* counts = (unsigned*)d_ws;
    unsigned* recs   = counts + NBINS;

    hipMemsetAsync(counts, 0, NBINS * sizeof(unsigned), stream);
    k_scatter<<<(PTS + 255) / 256, 256, 0, stream>>>(points, labels, counts, recs,
                                                     pos, pemb, out);
    k_gather<<<NBLK, 256, 0, stream>>>(counts, recs, pos, pemb, out);
}

// Round 10
// 99.394 us; speedup vs baseline: 1.0418x; 1.0418x over previous
//
#include <hip/hip_runtime.h>

// FastSAM3DPromptEncoder: out[b,n,c] = pos_embed[0,c,z,y,x] + point_emb[labels[b,n],c]
// (z,y,x) = clamp(trunc(points[b,n,:]), 0, 63).
//
// Counting-sort points by 64-B-line key (z,y,x>>4) into fixed-capacity bin
// segments (single atomic scatter pass), then bin-centric gather:
// 8 bins/block (2048 blocks), double-buffered LDS staged via
// global_load_lds DMA (no VGPR roundtrip, no ds_write tail). LDS layout is
// channel-major [c][16] with an x-quad XOR swizzle applied on BOTH the
// per-lane global source and the phase-2 read (rule: both-sides-or-neither).

constexpr int B_ = 32;
constexpr int N_ = 4096;
constexpr int C_ = 256;
constexpr int GD = 64;
constexpr int PTS = B_ * N_;               // 131072
constexpr int CELLS = GD * GD * GD;        // 262144 (channel stride)
constexpr int NBINS = GD * GD * (GD / 16); // 16384 line keys
constexpr int CAP = 64;                    // slots per bin (avg 8; P(>64)~1e-33)
constexpr int BPB = 8;                     // bins per block
constexpr int NBLK = NBINS / BPB;          // 2048 blocks

typedef float f32x4 __attribute__((ext_vector_type(4)));  // native vec for nt-store

__device__ __forceinline__ int clamp63(float v) {
    int i = (int)v;
    return min(max(i, 0), GD - 1);
}

__device__ __forceinline__ size_t linebase(int bin) {
    return ((size_t)(bin >> 8) << 12) | ((size_t)((bin >> 2) & 63) << 6) |
           ((size_t)(bin & 3) << 4);
}

// ---- K1: scatter packed point records into fixed-capacity bin segments ----
// rec = p (17b) | lab (1b @17) | x&15 (4b @18)
__global__ __launch_bounds__(256) void k_scatter(const float* __restrict__ points,
                                                 const int* __restrict__ labels,
                                                 unsigned* __restrict__ counts,
                                                 unsigned* __restrict__ recs,
                                                 const float* __restrict__ pos,
                                                 const float* __restrict__ pemb,
                                                 float* __restrict__ out) {
    int p = blockIdx.x * blockDim.x + threadIdx.x;
    if (p >= PTS) return;
    int zi = clamp63(points[p * 3 + 0]);
    int yi = clamp63(points[p * 3 + 1]);
    int xi = clamp63(points[p * 3 + 2]);
    int key = (zi << 8) | (yi << 2) | (xi >> 4);
    int lab = labels[p];
    unsigned slot = atomicAdd(&counts[key], 1u);
    if (slot < CAP) {
        recs[key * CAP + slot] =
            (unsigned)p | ((unsigned)lab << 17) | ((unsigned)(xi & 15) << 18);
    } else {
        // statistically unreachable overflow: write this point's row directly
        const int cell = (zi << 12) | (yi << 6) | xi;
        for (int c = 0; c < C_; ++c)
            out[(size_t)p * C_ + c] = pos[(size_t)c * CELLS + cell] + pemb[lab * C_ + c];
    }
}

// ---- K2: DMA-staged bin-centric gather. 8 bins/block, dbuf LDS ----
// LDS: tile[buf][c][16], where LDS[c][4*xq+t] = global[c][4*(xq ^ sq(c)) + t],
// sq(c) = (c>>2)&3. Staging: wave w, inst i covers channels 64w+16i..+15;
// lane l -> channel chunk+(l>>2), LDS quad l&3, global quad (l&3)^((l>>4)&3).
__global__ __launch_bounds__(256) void k_gather(const unsigned* __restrict__ counts,
                                                const unsigned* __restrict__ recs,
                                                const float* __restrict__ pos,
                                                const float* __restrict__ pemb,
                                                float* __restrict__ out) {
    __shared__ float tile[2][C_ * 16];      // 2 x 16 KB

    // XCD-chunked swizzle: each XCD owns a contiguous bin super-range.
    const int b    = blockIdx.x;
    const int swz  = (b & 7) * (NBLK >> 3) + (b >> 3);
    const int bin0 = swz * BPB;

    const int tid = threadIdx.x;
    const int w   = tid >> 6;
    const int l   = tid & 63;

    // point_emb rows for this lane's 4 channels, hoisted to registers
    const float4 te0 = *reinterpret_cast<const float4*>(pemb + 4 * l);
    const float4 te1 = *reinterpret_cast<const float4*>(pemb + C_ + 4 * l);

    // staging lane constants
    const int lsub = l >> 2;                                  // channel-in-chunk
    const int gq   = (((l & 3) ^ ((l >> 4) & 3)) << 2);       // swizzled global x (floats)

    auto stage = [&](float* lbuf, int bin) {
        const size_t lb = linebase(bin);
        #pragma unroll
        for (int i = 0; i < 4; ++i) {
            const int chunk = (w << 6) + (i << 4);            // wave-uniform
            const float* src = pos + (size_t)(chunk + lsub) * CELLS + lb + gq;
            float* dst = lbuf + chunk * 16;                   // wave-uniform base
            __builtin_amdgcn_global_load_lds(
                (const __attribute__((address_space(1))) unsigned int*)src,
                (__attribute__((address_space(3))) unsigned int*)dst,
                16, 0, 0);
        }
    };

    auto phase2 = [&](int bin, const float* tcur) {
        const unsigned cnt   = min(counts[bin], (unsigned)CAP);
        const unsigned start = (unsigned)bin * CAP;
        const unsigned end   = start + cnt;
        for (unsigned i = start + w; i < end; i += 4) {
            const unsigned rec = recs[i];            // wave-uniform broadcast
            const unsigned p   = rec & 0x1FFFFu;
            const unsigned o   = rec >> 18;          // 0..15
            const float4 te = ((rec >> 17) & 1u) ? te1 : te0;
            const int xi = ((((int)o >> 2) ^ (l & 3)) << 2) | ((int)o & 3);
            f32x4 rr;
            rr.x = tcur[(4 * l + 0) * 16 + xi] + te.x;
            rr.y = tcur[(4 * l + 1) * 16 + xi] + te.y;
            rr.z = tcur[(4 * l + 2) * 16 + xi] + te.z;
            rr.w = tcur[(4 * l + 3) * 16 + xi] + te.w;
            __builtin_nontemporal_store(rr,
                reinterpret_cast<f32x4*>(out + (size_t)p * C_ + 4 * l));
        }
    };

    // prologue: DMA bin0 into tile[0]; barrier drains vmcnt -> ready
    stage(tile[0], bin0);
    __syncthreads();

    #pragma unroll
    for (int k = 0; k < BPB; ++k) {
        const int cur = k & 1;
        if (k + 1 < BPB) stage(tile[cur ^ 1], bin0 + k + 1);  // DMA in flight
        phase2(bin0 + k, tile[cur]);                          // compute current
        __syncthreads();   // drains this iter's DMA; next tile ready
    }
}

// ---- fallback if ws too small ----
__global__ __launch_bounds__(256) void k_naive(const float* __restrict__ points,
                                               const int* __restrict__ labels,
                                               const float* __restrict__ pos,
                                               const float* __restrict__ pemb,
                                               float* __restrict__ out) {
    const int t    = blockIdx.x * blockDim.x + threadIdx.x;
    const int p    = t >> 6;
    const int lane = t & 63;
    const int c4   = lane << 2;
    if (p >= PTS) return;
    int zi = clamp63(points[p * 3 + 0]);
    int yi = clamp63(points[p * 3 + 1]);
    int xi = clamp63(points[p * 3 + 2]);
    const int cell = (zi << 12) | (yi << 6) | xi;
    const int lab  = labels[p];
    const float4 te = *reinterpret_cast<const float4*>(pemb + lab * C_ + c4);
    const float* g = pos + cell;
    float4 r;
    r.x = g[(c4 + 0) * CELLS] + te.x;
    r.y = g[(c4 + 1) * CELLS] + te.y;
    r.z = g[(c4 + 2) * CELLS] + te.z;
    r.w = g[(c4 + 3) * CELLS] + te.w;
    *reinterpret_cast<float4*>(out + p * C_ + c4) = r;
}

extern "C" void kernel_launch(void* const* d_in, const int* in_sizes, int n_in,
                              void* d_out, int out_size, void* d_ws, size_t ws_size,
                              hipStream_t stream) {
    const float* points = (const float*)d_in[0];
    const int*   labels = (const int*)d_in[1];
    const float* pos    = (const float*)d_in[2];
    const float* pemb   = (const float*)d_in[3];
    float*       out    = (float*)d_out;

    // ws layout: counts[NBINS] | recs[NBINS*CAP]
    const size_t need = (size_t)(NBINS + NBINS * CAP) * sizeof(unsigned);
    if (ws_size < need) {
        const int total = PTS * 64;
        k_naive<<<(total + 255) / 256, 256, 0, stream>>>(points, labels, pos, pemb, out);
        return;
    }
    unsigned* counts = (unsigned*)d_ws;
    unsigned* recs   = counts + NBINS;

    hipMemsetAsync(counts, 0, NBINS * sizeof(unsigned), stream);
    k_scatter<<<(PTS + 255) / 256, 256, 0, stream>>>(points, labels, counts, recs,
                                                     pos, pemb, out);
    k_gather<<<NBLK, 256, 0, stream>>>(counts, recs, pos, pemb, out);
}

// Round 11
// 96.259 us; speedup vs baseline: 1.0757x; 1.0326x over previous
//
#include <hip/hip_runtime.h>

// FastSAM3DPromptEncoder: out[b,n,c] = pos_embed[0,c,z,y,x] + point_emb[labels[b,n],c]
// (z,y,x) = clamp(trunc(points[b,n,:]), 0, 63).
//
// Counting-sort points by 64-B-line key (z,y,x>>4) into fixed-capacity bin
// segments (single atomic scatter pass), then bin-centric gather:
// 8 bins/block, double-buffered LDS tile, depth-1 software pipeline
// (round-8 structure), but 512-thread blocks -> 4 blocks/CU x 8 waves =
// 32 waves/CU (100% occupancy; round 8 was LDS-capped at 50%).

constexpr int B_ = 32;
constexpr int N_ = 4096;
constexpr int C_ = 256;
constexpr int GD = 64;
constexpr int PTS = B_ * N_;               // 131072
constexpr int CELLS = GD * GD * GD;        // 262144 (channel stride)
constexpr int NBINS = GD * GD * (GD / 16); // 16384 line keys
constexpr int CAP = 64;                    // slots per bin (avg 8; P(>64)~1e-33)
constexpr int BPB = 8;                     // bins per block
constexpr int NBLK = NBINS / BPB;          // 2048 blocks
constexpr int TP = 260;                    // padded tile row stride (floats)
constexpr int TPB = 512;                   // threads per block (8 waves)

typedef float f32x4 __attribute__((ext_vector_type(4)));  // native vec for nt-store

__device__ __forceinline__ int clamp63(float v) {
    int i = (int)v;
    return min(max(i, 0), GD - 1);
}

__device__ __forceinline__ size_t linebase(int bin) {
    return ((size_t)(bin >> 8) << 12) | ((size_t)((bin >> 2) & 63) << 6) |
           ((size_t)(bin & 3) << 4);
}

// ---- K1: scatter packed point records into fixed-capacity bin segments ----
// rec = p (17b) | lab (1b @17) | x&15 (4b @18)
__global__ __launch_bounds__(256) void k_scatter(const float* __restrict__ points,
                                                 const int* __restrict__ labels,
                                                 unsigned* __restrict__ counts,
                                                 unsigned* __restrict__ recs,
                                                 const float* __restrict__ pos,
                                                 const float* __restrict__ pemb,
                                                 float* __restrict__ out) {
    int p = blockIdx.x * blockDim.x + threadIdx.x;
    if (p >= PTS) return;
    int zi = clamp63(points[p * 3 + 0]);
    int yi = clamp63(points[p * 3 + 1]);
    int xi = clamp63(points[p * 3 + 2]);
    int key = (zi << 8) | (yi << 2) | (xi >> 4);
    int lab = labels[p];
    unsigned slot = atomicAdd(&counts[key], 1u);
    if (slot < CAP) {
        recs[key * CAP + slot] =
            (unsigned)p | ((unsigned)lab << 17) | ((unsigned)(xi & 15) << 18);
    } else {
        // statistically unreachable overflow: write this point's row directly
        const int cell = (zi << 12) | (yi << 6) | xi;
        for (int c = 0; c < C_; ++c)
            out[(size_t)p * C_ + c] = pos[(size_t)c * CELLS + cell] + pemb[lab * C_ + c];
    }
}

// ---- K2: pipelined bin-centric gather. 8 bins/block, dbuf LDS, 8 waves ----
__global__ __launch_bounds__(TPB, 8) void k_gather(const unsigned* __restrict__ counts,
                                                   const unsigned* __restrict__ recs,
                                                   const float* __restrict__ pos,
                                                   const float* __restrict__ pemb,
                                                   float* __restrict__ out) {
    __shared__ float tile[2][16 * TP];      // 2 x 16.6 KB

    // XCD-chunked swizzle: each XCD owns a contiguous bin super-range.
    const int b    = blockIdx.x;
    const int swz  = (b & 7) * (NBLK >> 3) + (b >> 3);
    const int bin0 = swz * BPB;

    const int tid  = threadIdx.x;
    const int w    = tid >> 6;              // 0..7
    const int l    = tid & 63;
    const int o4   = (tid & 3) << 2;        // x-offset group for staging
    const int c0   = tid >> 2;              // 0..127: first staged channel
    // thread stages channels c0 and c0+128 at x-quad o4

    // point_emb rows for this lane's 4 channels, hoisted to registers
    const float4 te0 = *reinterpret_cast<const float4*>(pemb + 4 * l);
    const float4 te1 = *reinterpret_cast<const float4*>(pemb + C_ + 4 * l);

#define LOADBIN(r0, r1, BIN) {                                                      \
        const size_t lb_ = linebase(BIN);                                           \
        r0 = *reinterpret_cast<const float4*>(pos + (size_t)(c0      ) * CELLS + lb_ + o4); \
        r1 = *reinterpret_cast<const float4*>(pos + (size_t)(c0 + 128) * CELLS + lb_ + o4); \
    }
#define WRITEBIN(r0, r1, DST) {                                                     \
        float* t_ = (DST);                                                          \
        t_[(o4 + 0) * TP + c0      ] = r0.x; t_[(o4 + 1) * TP + c0      ] = r0.y;   \
        t_[(o4 + 2) * TP + c0      ] = r0.z; t_[(o4 + 3) * TP + c0      ] = r0.w;   \
        t_[(o4 + 0) * TP + c0 + 128] = r1.x; t_[(o4 + 1) * TP + c0 + 128] = r1.y;   \
        t_[(o4 + 2) * TP + c0 + 128] = r1.z; t_[(o4 + 3) * TP + c0 + 128] = r1.w;   \
    }

    auto phase2 = [&](int bin, const float* tcur) {
        const unsigned cnt   = min(counts[bin], (unsigned)CAP);
        const unsigned start = (unsigned)bin * CAP;
        const unsigned end   = start + cnt;
        for (unsigned i = start + w; i < end; i += 8) {
            const unsigned rec = recs[i];            // wave-uniform broadcast
            const unsigned p   = rec & 0x1FFFFu;
            const unsigned o   = rec >> 18;
            const float4 te = ((rec >> 17) & 1u) ? te1 : te0;
            const float4 v  = *reinterpret_cast<const float4*>(tcur + o * TP + 4 * l);
            f32x4 rr;
            rr.x = v.x + te.x; rr.y = v.y + te.y; rr.z = v.z + te.z; rr.w = v.w + te.w;
            __builtin_nontemporal_store(rr,
                reinterpret_cast<f32x4*>(out + (size_t)p * C_ + 4 * l));
        }
    };

    float4 ra0, ra1;   // staging registers (2 float4 per thread)

    // prologue: load + stage bin0 into tile[0]
    LOADBIN(ra0, ra1, bin0);
    WRITEBIN(ra0, ra1, tile[0]);

    for (int k = 0; k < BPB; ++k) {
        const int cur = k & 1;
        // issue next bin's loads (stay in flight across barrier + phase 2)
        if (k + 1 < BPB) LOADBIN(ra0, ra1, bin0 + k + 1);
        __syncthreads();   // tile[cur] fully staged; prev phase-2 done

        phase2(bin0 + k, tile[cur]);

        // write the prefetched bin into the other buffer (WAR safe: last
        // reader of tile[cur^1] finished before the barrier above)
        if (k + 1 < BPB) WRITEBIN(ra0, ra1, tile[cur ^ 1]);
    }
#undef LOADBIN
#undef WRITEBIN
}

// ---- fallback if ws too small ----
__global__ __launch_bounds__(256) void k_naive(const float* __restrict__ points,
                                               const int* __restrict__ labels,
                                               const float* __restrict__ pos,
                                               const float* __restrict__ pemb,
                                               float* __restrict__ out) {
    const int t    = blockIdx.x * blockDim.x + threadIdx.x;
    const int p    = t >> 6;
    const int lane = t & 63;
    const int c4   = lane << 2;
    if (p >= PTS) return;
    int zi = clamp63(points[p * 3 + 0]);
    int yi = clamp63(points[p * 3 + 1]);
    int xi = clamp63(points[p * 3 + 2]);
    const int cell = (zi << 12) | (yi << 6) | xi;
    const int lab  = labels[p];
    const float4 te = *reinterpret_cast<const float4*>(pemb + lab * C_ + c4);
    const float* g = pos + cell;
    float4 r;
    r.x = g[(c4 + 0) * CELLS] + te.x;
    r.y = g[(c4 + 1) * CELLS] + te.y;
    r.z = g[(c4 + 2) * CELLS] + te.z;
    r.w = g[(c4 + 3) * CELLS] + te.w;
    *reinterpret_cast<float4*>(out + p * C_ + c4) = r;
}

extern "C" void kernel_launch(void* const* d_in, const int* in_sizes, int n_in,
                              void* d_out, int out_size, void* d_ws, size_t ws_size,
                              hipStream_t stream) {
    const float* points = (const float*)d_in[0];
    const int*   labels = (const int*)d_in[1];
    const float* pos    = (const float*)d_in[2];
    const float* pemb   = (const float*)d_in[3];
    float*       out    = (float*)d_out;

    // ws layout: counts[NBINS] | recs[NBINS*CAP]
    const size_t need = (size_t)(NBINS + NBINS * CAP) * sizeof(unsigned);
    if (ws_size < need) {
        const int total = PTS * 64;
        k_naive<<<(total + 255) / 256, 256, 0, stream>>>(points, labels, pos, pemb, out);
        return;
    }
    unsigned* counts = (unsigned*)d_ws;
    unsigned* recs   = counts + NBINS;

    hipMemsetAsync(counts, 0, NBINS * sizeof(unsigned), stream);
    k_scatter<<<(PTS + 255) / 256, 256, 0, stream>>>(points, labels, counts, recs,
                                                     pos, pemb, out);
    k_gather<<<NBLK, TPB, 0, stream>>>(counts, recs, pos, pemb, out);
}